// Round 9
// baseline (309.734 us; speedup 1.0000x reference)
//
#include <hip/hip_runtime.h>
#include <hip/hip_bf16.h>

typedef unsigned short u16;
typedef __bf16 bf16x8 __attribute__((ext_vector_type(8)));
typedef float f32x4 __attribute__((ext_vector_type(4)));

#define BATCH 16
#define C 256
#define NTOK 4096      // H*W
#define CN 1048576     // C*NTOK

__device__ __forceinline__ u16 f2b(float f) {
  __hip_bfloat16 h = __float2bfloat16(f);
  return __builtin_bit_cast(u16, h);
}
__device__ __forceinline__ float b2f(u16 u) {
  unsigned int x = ((unsigned int)u) << 16;
  return __builtin_bit_cast(float, x);
}

// async global->LDS, 16B per lane. LDS dest must be wave-uniform base
// (HW adds lane*16); global src is per-lane.
__device__ __forceinline__ void glds16(const u16* g, u16* l) {
  __builtin_amdgcn_global_load_lds(
      (const __attribute__((address_space(1))) unsigned int*)(g),
      (__attribute__((address_space(3))) unsigned int*)(l), 16, 0, 0);
}

// ---------------------------------------------------------------------------
// prep_x: x f32 [B][C][N] -> xbf [B][C][N], xT [B][N][C]; row partial sums
// atomically into rws (rws zeroed by prep_w, launched before).
__global__ __launch_bounds__(256) void prep_x_kernel(
    const float* __restrict__ x, u16* __restrict__ xbf, u16* __restrict__ xT,
    float* __restrict__ rws) {
  __shared__ float t[32][33];
  int b = blockIdx.z;
  int c0 = blockIdx.y * 32, n0 = blockIdx.x * 32;
  int tid = threadIdx.x;
  int i = tid >> 3, j4 = (tid & 7) * 4;
  const float* xb = x + (long)b * CN;
  float4 v = *(const float4*)(xb + (long)(c0 + i) * NTOK + n0 + j4);
  ushort4 bv;
  bv.x = f2b(v.x); bv.y = f2b(v.y); bv.z = f2b(v.z); bv.w = f2b(v.w);
  *(ushort4*)(xbf + (long)b * CN + (long)(c0 + i) * NTOK + n0 + j4) = bv;
  t[i][j4 + 0] = v.x; t[i][j4 + 1] = v.y; t[i][j4 + 2] = v.z; t[i][j4 + 3] = v.w;
  __syncthreads();
  ushort4 o;
  o.x = f2b(t[j4 + 0][i]); o.y = f2b(t[j4 + 1][i]);
  o.z = f2b(t[j4 + 2][i]); o.w = f2b(t[j4 + 3][i]);
  *(ushort4*)(xT + (long)b * CN + (long)(n0 + i) * C + c0 + j4) = o;
  if (tid < 32) {
    float s = 0.f;
#pragma unroll
    for (int j = 0; j < 32; ++j) s += t[tid][j];
    atomicAdd(&rws[b * C + c0 + tid], s);
  }
}

// ---------------------------------------------------------------------------
__global__ __launch_bounds__(256) void prep_w_kernel(
    const float* __restrict__ qkv_w, const float* __restrict__ proj_w,
    const float* __restrict__ conv_w, u16* __restrict__ Wq, u16* __restrict__ Wk,
    u16* __restrict__ WvT, u16* __restrict__ Pw, u16* __restrict__ cw,
    float* __restrict__ rws, u16* __restrict__ zbuf) {
  int idx = blockIdx.x * 256 + threadIdx.x;
  if (idx < 4096) rws[idx] = 0.f;
  if (idx < 256) zbuf[idx] = 0;
  if (idx < 65536) {
    Wq[idx] = f2b(qkv_w[idx]);
  } else if (idx < 131072) {
    int e = idx - 65536;
    Wk[e] = f2b(qkv_w[65536 + e]);
  } else if (idx < 196608) {
    int e = idx - 131072;
    int i = e >> 8, d = e & 255;
    WvT[e] = f2b(qkv_w[131072 + d * 256 + i]);
  } else if (idx < 262144) {
    int e = idx - 196608;
    Pw[e] = f2b(proj_w[e]);
  } else if (idx < 851968) {
    int e = idx - 262144;
    int o = e / 2304;
    int rem = e - o * 2304;
    int tap = rem >> 8, i = rem & 255;
    cw[e] = f2b(conv_w[o * 2304 + i * 9 + tap]);
  }
}

// bias_uw: u[b][d] = Wk[d,:]*r[b,:] ; w[b][c] = Wq[c,:]*r[b,:]
__global__ __launch_bounds__(512) void bias_uw_kernel(
    const float* __restrict__ qkv_w, const float* __restrict__ r,
    float* __restrict__ u, float* __restrict__ w) {
  int b = blockIdx.x, t = threadIdx.x;
  const float* rb = r + b * C;
  if (t < 256) {
    float s = 0.f;
    for (int i = 0; i < C; ++i) s += qkv_w[(256 + t) * 256 + i] * rb[i];
    u[b * C + t] = s;
  } else {
    int c = t - 256;
    float s = 0.f;
    for (int i = 0; i < C; ++i) s += qkv_w[c * 256 + i] * rb[i];
    w[b * C + c] = s;
  }
}

// ---------------------------------------------------------------------------
// Generic GEMM C = A*B^T (both K-contiguous), 128x128 tile, BK=32, 4 waves,
// global_load_lds staging + slot-XOR swizzle, double-buffered.
// EPI 0: f32 partial store at (b*gridDim.y+ks)*sC. EPI 1: bf16. EPI 2: S-epi.
template <int EPI>
__global__ __launch_bounds__(256, 2) void gemm_glds_kernel(
    const u16* __restrict__ A, const u16* __restrict__ B, void* __restrict__ Cv,
    int K, int lda, int ldb, int ldc, int tilesN, long sA, long sB, long sC,
    float scale, const float* __restrict__ e1, const float* __restrict__ e2,
    const float* __restrict__ e3, const float* __restrict__ e4, int e34stride) {
  int b = blockIdx.z, ks = blockIdx.y;
  A += (long)b * sA + (long)ks * K;
  B += (long)b * sB + (long)ks * K;
  int ty = blockIdx.x / tilesN, tx = blockIdx.x % tilesN;
  int row0 = ty * 128, col0 = tx * 128;

  __shared__ u16 lA[2][4096];
  __shared__ u16 lB[2][4096];

  int tid = threadIdx.x;
  int lane = tid & 63, wv = tid >> 6;
  int wm = wv >> 1, wn = wv & 1;
  int fr = lane & 15, kq = lane >> 4;
  int kqs = kq ^ ((fr >> 1) & 3);

  int c0 = wv * 128 + lane, c1 = c0 + 64;
  int r0s = c0 >> 2, r1s = c1 >> 2;
  int ls0 = (c0 & 3) ^ ((r0s >> 1) & 3);
  int ls1 = (c1 & 3) ^ ((r1s >> 1) & 3);
  const u16* pA0 = A + (long)(row0 + r0s) * lda + ls0 * 8;
  const u16* pA1 = A + (long)(row0 + r1s) * lda + ls1 * 8;
  const u16* pB0 = B + (long)(col0 + r0s) * ldb + ls0 * 8;
  const u16* pB1 = B + (long)(col0 + r1s) * ldb + ls1 * 8;
  int dst0 = wv * 1024, dst1 = wv * 1024 + 512;

  f32x4 acc[4][4] = {};

  auto STAGE = [&](int buf, int t) {
    int k0 = t << 5;
    glds16(pA0 + k0, &lA[buf][dst0]);
    glds16(pA1 + k0, &lA[buf][dst1]);
    glds16(pB0 + k0, &lB[buf][dst0]);
    glds16(pB1 + k0, &lB[buf][dst1]);
  };
  auto COMPUTE = [&](int buf) {
    bf16x8 af[4], bfr[4];
#pragma unroll
    for (int m = 0; m < 4; ++m)
      af[m] = *(const bf16x8*)&lA[buf][(wm * 64 + m * 16 + fr) * 32 + kqs * 8];
#pragma unroll
    for (int n = 0; n < 4; ++n)
      bfr[n] = *(const bf16x8*)&lB[buf][(wn * 64 + n * 16 + fr) * 32 + kqs * 8];
#pragma unroll
    for (int m = 0; m < 4; ++m)
#pragma unroll
      for (int n = 0; n < 4; ++n)
        acc[m][n] = __builtin_amdgcn_mfma_f32_16x16x32_bf16(af[m], bfr[n], acc[m][n], 0, 0, 0);
  };

  int nk = K >> 5, cur = 0;
  STAGE(0, 0);
  __syncthreads();
  for (int t = 0; t < nk; ++t) {
    if (t + 1 < nk) STAGE(cur ^ 1, t + 1);
    COMPUTE(cur);
    __syncthreads();
    cur ^= 1;
  }

  if (EPI == 0) {
    float* Cb = (float*)Cv + ((long)b * gridDim.y + ks) * sC;
#pragma unroll
    for (int m = 0; m < 4; ++m)
#pragma unroll
      for (int n = 0; n < 4; ++n)
#pragma unroll
        for (int r = 0; r < 4; ++r) {
          int gr = row0 + wm * 64 + m * 16 + kq * 4 + r;
          int gc = col0 + wn * 64 + n * 16 + fr;
          Cb[(long)gr * ldc + gc] = acc[m][n][r];
        }
  } else if (EPI == 1) {
    __hip_bfloat16* Cb = (__hip_bfloat16*)Cv + (long)b * sC;
#pragma unroll
    for (int m = 0; m < 4; ++m)
#pragma unroll
      for (int n = 0; n < 4; ++n)
#pragma unroll
        for (int r = 0; r < 4; ++r) {
          int gr = row0 + wm * 64 + m * 16 + kq * 4 + r;
          int gc = col0 + wn * 64 + n * 16 + fr;
          Cb[(long)gr * ldc + gc] = __float2bfloat16(acc[m][n][r]);
        }
  } else if (EPI == 2) {
    float* Cb = (float*)Cv + (long)b * sC;
    const float* ub = e3 + (long)b * e34stride;
    const float* wb = e4 + (long)b * e34stride;
#pragma unroll
    for (int m = 0; m < 4; ++m)
#pragma unroll
      for (int n = 0; n < 4; ++n)
#pragma unroll
        for (int r = 0; r < 4; ++r) {
          int gr = row0 + wm * 64 + m * 16 + kq * 4 + r;
          int gc = col0 + wn * 64 + n * 16 + fr;
          float v = acc[m][n][r] + e1[gr] * ub[gc] + e2[gc] * wb[gr] +
                    4096.0f * e1[gr] * e2[gc];
          Cb[(long)gr * ldc + gc] = v * scale;
        }
  }
}

// reduce 4 f32 split-K partials -> Gbf bf16. grid (64, B), block 256
__global__ __launch_bounds__(256) void reduceG_kernel(
    const float* __restrict__ Gp, u16* __restrict__ G) {
  int b = blockIdx.y;
  int e = blockIdx.x * 1024 + threadIdx.x * 4;
  const float* base = Gp + (long)b * 262144;
  float4 s = *(const float4*)(base + e);
#pragma unroll
  for (int sl = 1; sl < 4; ++sl) {
    float4 v = *(const float4*)(base + sl * 65536 + e);
    s.x += v.x; s.y += v.y; s.z += v.z; s.w += v.w;
  }
  ushort4 o;
  o.x = f2b(s.x); o.y = f2b(s.y); o.z = f2b(s.z); o.w = f2b(s.w);
  *(ushort4*)(G + (long)b * 65536 + e) = o;
}

// ---------------------------------------------------------------------------
// softmax over rows of S -> attn^T bf16 (attnT[d][c] = attn[c][d])
__global__ __launch_bounds__(256) void softmax_kernel(const float* __restrict__ S,
                                                      u16* __restrict__ attnT) {
  int row = blockIdx.x;
  int t = threadIdx.x;
  float v = S[(long)row * C + t];
  __shared__ float red[256];
  red[t] = v; __syncthreads();
  for (int st = 128; st > 0; st >>= 1) {
    if (t < st) red[t] = fmaxf(red[t], red[t + st]);
    __syncthreads();
  }
  float mx = red[0];
  __syncthreads();
  float e = __expf(v - mx);
  red[t] = e; __syncthreads();
  for (int st = 128; st > 0; st >>= 1) {
    if (t < st) red[t] += red[t + st];
    __syncthreads();
  }
  float inv = 1.0f / red[0];
  int b = row >> 8, c = row & 255;
  attnT[(long)b * 65536 + t * 256 + c] = f2b(e * inv);
}

// cbias[b][j] = proj_b[j] + sum_d M[b][j][d]*qkv_b[512+d]
__global__ __launch_bounds__(256) void cbias_kernel(const u16* __restrict__ M,
                                                    const float* __restrict__ qkv_b,
                                                    const float* __restrict__ proj_b,
                                                    float* __restrict__ cb) {
  int b = blockIdx.x, j = threadIdx.x;
  const u16* m = M + (long)b * 65536 + (long)j * 256;
  float s = 0.f;
  for (int d = 0; d < C; ++d) s += b2f(m[d]) * qkv_b[512 + d];
  cb[b * C + j] = proj_b[j] + s;
}

// ---------------------------------------------------------------------------
// Fused conv3x3 implicit-GEMM + attention-output GEMM, BK=64.
// r8 was LDS-BW-bound (96KB LDS traffic/block-step vs 64KB MFMA-equivalent).
// v3: A-operand fragments load GLOBAL->REGISTER directly (no LDS round-trip):
//  - per-lane frag addr = row(fr)-base + kq*8; conv K-stream is LINEAR
//    (+64 u16/step across taps&chunks) -> 4 pointers bumped 128B/step.
//  - double-banked regs aR0/aR1, static parity over unrolled j (rule #20).
// LDS holds only B (2x16KB). B staging/swizzle/barriers identical to r8.
__global__ __launch_bounds__(256, 2) void convattn_kernel(
    const u16* __restrict__ xT, const u16* __restrict__ cw,
    const u16* __restrict__ W2, const u16* __restrict__ zbuf,
    const float* __restrict__ conv_b, const float* __restrict__ cb,
    float* __restrict__ out) {
  int b = blockIdx.y;
  int to = blockIdx.x >> 5;  // 0..1
  int tn = blockIdx.x & 31;  // 0..31
  int row0 = to * 128, col0 = tn * 128;
  const u16* xTb = xT + (long)b * CN;
  const u16* W2b = W2 + (long)b * 65536;

  __shared__ u16 lB[2][8192];   // [128][64] u16 per buffer (B only)

  int tid = threadIdx.x;
  int lane = tid & 63, w = tid >> 6;
  int wm = w >> 1, wn = w & 1;
  int fr = lane & 15, kq = lane >> 4;
  int fx = fr & 7;              // B-read swizzle (matches write)

  // B staging: wave stages rows [w*32, w*32+32), 4 glds of 8 rows each
  int lr = lane >> 3, sl = lane & 7;
  int ss = sl ^ lr;             // swizzled source slot

  const u16* pBt[4]; int hh[4], ww[4];
  const u16* zsrc = zbuf + ss * 8;
#pragma unroll
  for (int i = 0; i < 4; ++i) {
    int t = col0 + w * 32 + i * 8 + lr;
    hh[i] = t >> 6; ww[i] = t & 63;
    pBt[i] = xTb + (long)t * 256 + ss * 8;
  }
  int nb = col0 >> 8, jb = col0 & 255;

  // A direct-global per-lane fragment bases (conv stream; +64 u16 per step)
  const u16* aP[4];
#pragma unroll
  for (int m = 0; m < 4; ++m)
    aP[m] = cw + (long)(row0 + wm * 64 + m * 16 + fr) * 2304 + kq * 8;
  // attn A bases (switched in at step 36)
  const u16* aQ[4];
#pragma unroll
  for (int m = 0; m < 4; ++m)
    aQ[m] = xTb + (long)((row0 + wm * 64 + m * 16 + fr) * 16 + nb) * 256 + kq * 8;

  f32x4 acc[4][4] = {};
  const u16 *bt0, *bt1, *bt2, *bt3;

  auto set_tapB = [&](int tap) {
    int dh = tap / 3 - 1, dw = tap % 3 - 1;
    long sh = (long)(dh * 64 + dw) * 256;
    bool v0 = ((unsigned)(hh[0] + dh) < 64u) && ((unsigned)(ww[0] + dw) < 64u);
    bool v1 = ((unsigned)(hh[1] + dh) < 64u) && ((unsigned)(ww[1] + dw) < 64u);
    bool v2 = ((unsigned)(hh[2] + dh) < 64u) && ((unsigned)(ww[2] + dw) < 64u);
    bool v3 = ((unsigned)(hh[3] + dh) < 64u) && ((unsigned)(ww[3] + dw) < 64u);
    bt0 = v0 ? pBt[0] + sh : zsrc;
    bt1 = v1 ? pBt[1] + sh : zsrc;
    bt2 = v2 ? pBt[2] + sh : zsrc;
    bt3 = v3 ? pBt[3] + sh : zsrc;
  };
  auto set_attnB = [&]() {
    bt0 = W2b + (long)(jb + w * 32 + 0 + lr) * 256 + ss * 8;
    bt1 = W2b + (long)(jb + w * 32 + 8 + lr) * 256 + ss * 8;
    bt2 = W2b + (long)(jb + w * 32 + 16 + lr) * 256 + ss * 8;
    bt3 = W2b + (long)(jb + w * 32 + 24 + lr) * 256 + ss * 8;
  };

  auto STAGE_B = [&](int buf, int chunk) {
    int k = chunk * 64;
    glds16(bt0 + k, &lB[buf][(w * 32 + 0) * 64]);
    glds16(bt1 + k, &lB[buf][(w * 32 + 8) * 64]);
    glds16(bt2 + k, &lB[buf][(w * 32 + 16) * 64]);
    glds16(bt3 + k, &lB[buf][(w * 32 + 24) * 64]);
  };

  bf16x8 aR0[4][2], aR1[4][2];
  auto LOADA = [&](bf16x8 (&d)[4][2]) {
#pragma unroll
    for (int m = 0; m < 4; ++m) {
      d[m][0] = *(const bf16x8*)(aP[m]);
      d[m][1] = *(const bf16x8*)(aP[m] + 32);
    }
#pragma unroll
    for (int m = 0; m < 4; ++m) aP[m] += 64;
  };
  auto COMPUTE = [&](int buf, const bf16x8 (&a)[4][2]) {
    bf16x8 bf_[4][2];
#pragma unroll
    for (int n = 0; n < 4; ++n) {
      int row = wn * 64 + n * 16 + fr;
#pragma unroll
      for (int kh = 0; kh < 2; ++kh)
        bf_[n][kh] = *(const bf16x8*)&lB[buf][row * 64 + (((kh << 2) + kq) ^ fx) * 8];
    }
    __builtin_amdgcn_s_setprio(1);
#pragma unroll
    for (int kh = 0; kh < 2; ++kh)
#pragma unroll
      for (int m = 0; m < 4; ++m)
#pragma unroll
        for (int n = 0; n < 4; ++n)
          acc[m][n] = __builtin_amdgcn_mfma_f32_16x16x32_bf16(a[m][kh], bf_[n][kh], acc[m][n], 0, 0, 0);
    __builtin_amdgcn_s_setprio(0);
  };

  // prologue: B tap0 chunk0 staged; A step0 in aR0 (aP advances to step1)
  set_tapB(0);
  STAGE_B(0, 0);
  LOADA(aR0);
  asm volatile("s_waitcnt vmcnt(0)" ::: "memory");
  __builtin_amdgcn_sched_barrier(0);
  __builtin_amdgcn_s_barrier();
  __builtin_amdgcn_sched_barrier(0);

  int buf = 0;
#pragma unroll 1
  for (int T = 0; T < 10; ++T) {
#pragma unroll
    for (int j = 0; j < 4; ++j) {
      bool last = (T == 9) && (j == 3);
      if (!last) {
        if (j == 3) {
          if (T < 8) set_tapB(T + 1);
          else set_attnB();
          if (T == 8) {
#pragma unroll
            for (int m = 0; m < 4; ++m) aP[m] = aQ[m];  // A -> attn stream
          }
        }
        if ((j & 1) == 0) LOADA(aR1); else LOADA(aR0);   // prefetch A(t+1)
        STAGE_B(buf ^ 1, (j < 3) ? j + 1 : 0);           // prefetch B(t+1)
      }
      if ((j & 1) == 0) COMPUTE(buf, aR0); else COMPUTE(buf, aR1);
      asm volatile("s_waitcnt vmcnt(0)" ::: "memory");
      __builtin_amdgcn_sched_barrier(0);
      __builtin_amdgcn_s_barrier();
      __builtin_amdgcn_sched_barrier(0);
      buf ^= 1;
    }
  }

  float* ob = out + (long)b * CN;
  const float* cbb = cb + b * C;
#pragma unroll
  for (int m = 0; m < 4; ++m) {
    int go = row0 + wm * 64 + m * 16 + kq * 4;
#pragma unroll
    for (int nn = 0; nn < 4; ++nn) {
      int cc = wn * 64 + nn * 16 + fr;
      float cbv = cbb[jb + cc];
#pragma unroll
      for (int r = 0; r < 4; ++r)
        ob[(long)(go + r) * NTOK + col0 + cc] =
            acc[m][nn][r] + conv_b[go + r] + cbv;
    }
  }
}

// ---------------------------------------------------------------------------
extern "C" void kernel_launch(void* const* d_in, const int* in_sizes, int n_in,
                              void* d_out, int out_size, void* d_ws, size_t ws_size,
                              hipStream_t stream) {
  const float* x = (const float*)d_in[0];
  const float* qkv_w = (const float*)d_in[1];
  const float* qkv_b = (const float*)d_in[2];
  const float* proj_w = (const float*)d_in[3];
  const float* proj_b = (const float*)d_in[4];
  const float* conv_w = (const float*)d_in[5];
  const float* conv_b = (const float*)d_in[6];
  float* out = (float*)d_out;
  char* ws = (char*)d_ws;

  u16* xbf = (u16*)(ws);                    // 32 MB
  u16* xT = (u16*)(ws + 33554432);          // 32 MB
  u16* Gbf = (u16*)(ws + 67108864);         // 2 MB
  float* Gpart = (float*)(ws + 69206016);   // union w/ T1bf (dead after reduceG)
  u16* T1bf = (u16*)(ws + 69206016);
  float* Sf = (float*)(ws + 71303168);
  u16* attnT = (u16*)(ws + 75497472);
  u16* Mbf = (u16*)(ws + 77594624);
  u16* W2bf = (u16*)(ws + 79691776);
  u16* Wq = (u16*)(ws + 85983232);
  u16* Wk = (u16*)(ws + 86114304);
  u16* WvT = (u16*)(ws + 86245376);
  u16* Pw = (u16*)(ws + 86376448);
  u16* cw = (u16*)(ws + 86507520);
  float* rws = (float*)(ws + 87687168);
  float* uws = (float*)(ws + 87703552);
  float* wws = (float*)(ws + 87719936);
  float* cb = (float*)(ws + 87736320);
  u16* zbuf = (u16*)(ws + 87752704);

  prep_w_kernel<<<3328, 256, 0, stream>>>(qkv_w, proj_w, conv_w, Wq, Wk, WvT,
                                          Pw, cw, rws, zbuf);
  prep_x_kernel<<<dim3(128, 8, BATCH), 256, 0, stream>>>(x, xbf, xT, rws);
  bias_uw_kernel<<<BATCH, 512, 0, stream>>>(qkv_w, rws, uws, wws);

  // G = X*X^T per batch, split-K x4 -> f32 partials
  gemm_glds_kernel<0><<<dim3(4, 4, BATCH), 256, 0, stream>>>(
      xbf, xbf, Gpart, 1024, 4096, 4096, 256, 2, CN, CN, 65536,
      0.f, nullptr, nullptr, nullptr, nullptr, 0);
  reduceG_kernel<<<dim3(64, BATCH), 256, 0, stream>>>(Gpart, Gbf);

  // T1 = Wq * G  (G symmetric)
  gemm_glds_kernel<1><<<dim3(4, 1, BATCH), 256, 0, stream>>>(
      Wq, Gbf, T1bf, 256, 256, 256, 256, 2, 0, 65536, 65536,
      0.f, nullptr, nullptr, nullptr, nullptr, 0);
  // S = (T1 * Wk^T + bias terms) * scale
  gemm_glds_kernel<2><<<dim3(4, 1, BATCH), 256, 0, stream>>>(
      T1bf, Wk, Sf, 256, 256, 256, 256, 2, 65536, 0, 65536,
      0.0625f, qkv_b, qkv_b + 256, uws, wws, 256);

  softmax_kernel<<<BATCH * C, 256, 0, stream>>>(Sf, attnT);

  // M = Pw * attn   (B operand = attn^T)
  gemm_glds_kernel<1><<<dim3(4, 1, BATCH), 256, 0, stream>>>(
      Pw, attnT, Mbf, 256, 256, 256, 256, 2, 0, 65536, 65536,
      0.f, nullptr, nullptr, nullptr, nullptr, 0);
  cbias_kernel<<<BATCH, 256, 0, stream>>>(Mbf, qkv_b, proj_b, cb);
  // W2 = M * Wv     (B operand = WvT)
  gemm_glds_kernel<1><<<dim3(4, 1, BATCH), 256, 0, stream>>>(
      Mbf, WvT, W2bf, 256, 256, 256, 256, 2, 65536, 0, 65536,
      0.f, nullptr, nullptr, nullptr, nullptr, 0);

  // fused conv + attention-output, single store of out
  convattn_kernel<<<dim3(64, BATCH), 256, 0, stream>>>(xT, cw, W2bf, zbuf,
                                                       conv_b, cb, out);
}

// Round 10
// 216.087 us; speedup vs baseline: 1.4334x; 1.4334x over previous
//
#include <hip/hip_runtime.h>
#include <hip/hip_bf16.h>

typedef unsigned short u16;
typedef __bf16 bf16x8 __attribute__((ext_vector_type(8)));
typedef float f32x4 __attribute__((ext_vector_type(4)));

#define BATCH 16
#define C 256
#define NTOK 4096      // H*W
#define CN 1048576     // C*NTOK

__device__ __forceinline__ u16 f2b(float f) {
  __hip_bfloat16 h = __float2bfloat16(f);
  return __builtin_bit_cast(u16, h);
}
__device__ __forceinline__ float b2f(u16 u) {
  unsigned int x = ((unsigned int)u) << 16;
  return __builtin_bit_cast(float, x);
}

// async global->LDS, 16B per lane. LDS dest must be wave-uniform base
// (HW adds lane*16); global src is per-lane.
__device__ __forceinline__ void glds16(const u16* g, u16* l) {
  __builtin_amdgcn_global_load_lds(
      (const __attribute__((address_space(1))) unsigned int*)(g),
      (__attribute__((address_space(3))) unsigned int*)(l), 16, 0, 0);
}

// ---------------------------------------------------------------------------
// prep_x: x f32 [B][C][N] -> xbf [B][C][N], xT [B][N][C]; row partial sums
// atomically into rws (rws zeroed by prep_w, launched before).
__global__ __launch_bounds__(256) void prep_x_kernel(
    const float* __restrict__ x, u16* __restrict__ xbf, u16* __restrict__ xT,
    float* __restrict__ rws) {
  __shared__ float t[32][33];
  int b = blockIdx.z;
  int c0 = blockIdx.y * 32, n0 = blockIdx.x * 32;
  int tid = threadIdx.x;
  int i = tid >> 3, j4 = (tid & 7) * 4;
  const float* xb = x + (long)b * CN;
  float4 v = *(const float4*)(xb + (long)(c0 + i) * NTOK + n0 + j4);
  ushort4 bv;
  bv.x = f2b(v.x); bv.y = f2b(v.y); bv.z = f2b(v.z); bv.w = f2b(v.w);
  *(ushort4*)(xbf + (long)b * CN + (long)(c0 + i) * NTOK + n0 + j4) = bv;
  t[i][j4 + 0] = v.x; t[i][j4 + 1] = v.y; t[i][j4 + 2] = v.z; t[i][j4 + 3] = v.w;
  __syncthreads();
  ushort4 o;
  o.x = f2b(t[j4 + 0][i]); o.y = f2b(t[j4 + 1][i]);
  o.z = f2b(t[j4 + 2][i]); o.w = f2b(t[j4 + 3][i]);
  *(ushort4*)(xT + (long)b * CN + (long)(n0 + i) * C + c0 + j4) = o;
  if (tid < 32) {
    float s = 0.f;
#pragma unroll
    for (int j = 0; j < 32; ++j) s += t[tid][j];
    atomicAdd(&rws[b * C + c0 + tid], s);
  }
}

// ---------------------------------------------------------------------------
__global__ __launch_bounds__(256) void prep_w_kernel(
    const float* __restrict__ qkv_w, const float* __restrict__ proj_w,
    const float* __restrict__ conv_w, u16* __restrict__ Wq, u16* __restrict__ Wk,
    u16* __restrict__ WvT, u16* __restrict__ Pw, u16* __restrict__ cw,
    float* __restrict__ rws, u16* __restrict__ zbuf) {
  int idx = blockIdx.x * 256 + threadIdx.x;
  if (idx < 4096) rws[idx] = 0.f;
  if (idx < 256) zbuf[idx] = 0;
  if (idx < 65536) {
    Wq[idx] = f2b(qkv_w[idx]);
  } else if (idx < 131072) {
    int e = idx - 65536;
    Wk[e] = f2b(qkv_w[65536 + e]);
  } else if (idx < 196608) {
    int e = idx - 131072;
    int i = e >> 8, d = e & 255;
    WvT[e] = f2b(qkv_w[131072 + d * 256 + i]);
  } else if (idx < 262144) {
    int e = idx - 196608;
    Pw[e] = f2b(proj_w[e]);
  } else if (idx < 851968) {
    int e = idx - 262144;
    int o = e / 2304;
    int rem = e - o * 2304;
    int tap = rem >> 8, i = rem & 255;
    cw[e] = f2b(conv_w[o * 2304 + i * 9 + tap]);
  }
}

// ---------------------------------------------------------------------------
// Generic GEMM C = A*B^T (both K-contiguous), 128x128 tile, BK=32, 4 waves,
// global_load_lds staging + slot-XOR swizzle, double-buffered.
// EPI 0: f32 partial store at (b*gridDim.y+ks)*sC. EPI 1: bf16. EPI 2: S-epi.
template <int EPI>
__global__ __launch_bounds__(256, 2) void gemm_glds_kernel(
    const u16* __restrict__ A, const u16* __restrict__ B, void* __restrict__ Cv,
    int K, int lda, int ldb, int ldc, int tilesN, long sA, long sB, long sC,
    float scale, const float* __restrict__ e1, const float* __restrict__ e2,
    const float* __restrict__ e3, const float* __restrict__ e4, int e34stride) {
  int b = blockIdx.z, ks = blockIdx.y;
  A += (long)b * sA + (long)ks * K;
  B += (long)b * sB + (long)ks * K;
  int ty = blockIdx.x / tilesN, tx = blockIdx.x % tilesN;
  int row0 = ty * 128, col0 = tx * 128;

  __shared__ u16 lA[2][4096];
  __shared__ u16 lB[2][4096];

  int tid = threadIdx.x;
  int lane = tid & 63, wv = tid >> 6;
  int wm = wv >> 1, wn = wv & 1;
  int fr = lane & 15, kq = lane >> 4;
  int kqs = kq ^ ((fr >> 1) & 3);

  int c0 = wv * 128 + lane, c1 = c0 + 64;
  int r0s = c0 >> 2, r1s = c1 >> 2;
  int ls0 = (c0 & 3) ^ ((r0s >> 1) & 3);
  int ls1 = (c1 & 3) ^ ((r1s >> 1) & 3);
  const u16* pA0 = A + (long)(row0 + r0s) * lda + ls0 * 8;
  const u16* pA1 = A + (long)(row0 + r1s) * lda + ls1 * 8;
  const u16* pB0 = B + (long)(col0 + r0s) * ldb + ls0 * 8;
  const u16* pB1 = B + (long)(col0 + r1s) * ldb + ls1 * 8;
  int dst0 = wv * 1024, dst1 = wv * 1024 + 512;

  f32x4 acc[4][4] = {};

  auto STAGE = [&](int buf, int t) {
    int k0 = t << 5;
    glds16(pA0 + k0, &lA[buf][dst0]);
    glds16(pA1 + k0, &lA[buf][dst1]);
    glds16(pB0 + k0, &lB[buf][dst0]);
    glds16(pB1 + k0, &lB[buf][dst1]);
  };
  auto COMPUTE = [&](int buf) {
    bf16x8 af[4], bfr[4];
#pragma unroll
    for (int m = 0; m < 4; ++m)
      af[m] = *(const bf16x8*)&lA[buf][(wm * 64 + m * 16 + fr) * 32 + kqs * 8];
#pragma unroll
    for (int n = 0; n < 4; ++n)
      bfr[n] = *(const bf16x8*)&lB[buf][(wn * 64 + n * 16 + fr) * 32 + kqs * 8];
#pragma unroll
    for (int m = 0; m < 4; ++m)
#pragma unroll
      for (int n = 0; n < 4; ++n)
        acc[m][n] = __builtin_amdgcn_mfma_f32_16x16x32_bf16(af[m], bfr[n], acc[m][n], 0, 0, 0);
  };

  int nk = K >> 5, cur = 0;
  STAGE(0, 0);
  __syncthreads();
  for (int t = 0; t < nk; ++t) {
    if (t + 1 < nk) STAGE(cur ^ 1, t + 1);
    COMPUTE(cur);
    __syncthreads();
    cur ^= 1;
  }

  if (EPI == 0) {
    float* Cb = (float*)Cv + ((long)b * 4 + ks) * sC;
#pragma unroll
    for (int m = 0; m < 4; ++m)
#pragma unroll
      for (int n = 0; n < 4; ++n)
#pragma unroll
        for (int r = 0; r < 4; ++r) {
          int gr = row0 + wm * 64 + m * 16 + kq * 4 + r;
          int gc = col0 + wn * 64 + n * 16 + fr;
          Cb[(long)gr * ldc + gc] = acc[m][n][r];
        }
  } else if (EPI == 1) {
    __hip_bfloat16* Cb = (__hip_bfloat16*)Cv + (long)b * sC;
#pragma unroll
    for (int m = 0; m < 4; ++m)
#pragma unroll
      for (int n = 0; n < 4; ++n)
#pragma unroll
        for (int r = 0; r < 4; ++r) {
          int gr = row0 + wm * 64 + m * 16 + kq * 4 + r;
          int gc = col0 + wn * 64 + n * 16 + fr;
          Cb[(long)gr * ldc + gc] = __float2bfloat16(acc[m][n][r]);
        }
  } else if (EPI == 2) {
    float* Cb = (float*)Cv + (long)b * sC;
    const float* ub = e3 + (long)b * e34stride;
    const float* wb = e4 + (long)b * e34stride;
#pragma unroll
    for (int m = 0; m < 4; ++m)
#pragma unroll
      for (int n = 0; n < 4; ++n)
#pragma unroll
        for (int r = 0; r < 4; ++r) {
          int gr = row0 + wm * 64 + m * 16 + kq * 4 + r;
          int gc = col0 + wn * 64 + n * 16 + fr;
          float v = acc[m][n][r] + e1[gr] * ub[gc] + e2[gc] * wb[gr] +
                    4096.0f * e1[gr] * e2[gc];
          Cb[(long)gr * ldc + gc] = v * scale;
        }
  }
}

// ---------------------------------------------------------------------------
// reduceG + bias_uw merged (independent work, both ready at this point).
// grid (65, B): x<64 -> reduce 4 split-K partials into Gbf bf16;
// x==64 -> u[b][t]=Wk[t,:]*r[b,:], w[b][t]=Wq[t,:]*r[b,:] (t = threadIdx).
__global__ __launch_bounds__(256) void reduceG_bias_kernel(
    const float* __restrict__ Gp, u16* __restrict__ G,
    const float* __restrict__ qkv_w, const float* __restrict__ r,
    float* __restrict__ u, float* __restrict__ w) {
  int b = blockIdx.y;
  if (blockIdx.x < 64) {
    int e = blockIdx.x * 1024 + threadIdx.x * 4;
    const float* base = Gp + (long)b * 262144;
    float4 s = *(const float4*)(base + e);
#pragma unroll
    for (int sl = 1; sl < 4; ++sl) {
      float4 v = *(const float4*)(base + sl * 65536 + e);
      s.x += v.x; s.y += v.y; s.z += v.z; s.w += v.w;
    }
    ushort4 o;
    o.x = f2b(s.x); o.y = f2b(s.y); o.z = f2b(s.z); o.w = f2b(s.w);
    *(ushort4*)(G + (long)b * 65536 + e) = o;
  } else {
    int t = threadIdx.x;
    const float* rb = r + b * C;
    float su = 0.f, sw = 0.f;
    for (int i = 0; i < C; ++i) {
      float rv = rb[i];
      su += qkv_w[(256 + t) * 256 + i] * rv;
      sw += qkv_w[t * 256 + i] * rv;
    }
    u[b * C + t] = su;
    w[b * C + t] = sw;
  }
}

// ---------------------------------------------------------------------------
// softmax over rows of S -> attn^T bf16 (attnT[d][c] = attn[c][d])
__global__ __launch_bounds__(256) void softmax_kernel(const float* __restrict__ S,
                                                      u16* __restrict__ attnT) {
  int row = blockIdx.x;
  int t = threadIdx.x;
  float v = S[(long)row * C + t];
  __shared__ float red[256];
  red[t] = v; __syncthreads();
  for (int st = 128; st > 0; st >>= 1) {
    if (t < st) red[t] = fmaxf(red[t], red[t + st]);
    __syncthreads();
  }
  float mx = red[0];
  __syncthreads();
  float e = __expf(v - mx);
  red[t] = e; __syncthreads();
  for (int st = 128; st > 0; st >>= 1) {
    if (t < st) red[t] += red[t + st];
    __syncthreads();
  }
  float inv = 1.0f / red[0];
  int b = row >> 8, c = row & 255;
  attnT[(long)b * 65536 + t * 256 + c] = f2b(e * inv);
}

// cbias[b][j] = proj_b[j] + sum_d M[b][j][d]*qkv_b[512+d]
__global__ __launch_bounds__(256) void cbias_kernel(const u16* __restrict__ M,
                                                    const float* __restrict__ qkv_b,
                                                    const float* __restrict__ proj_b,
                                                    float* __restrict__ cb) {
  int b = blockIdx.x, j = threadIdx.x;
  const u16* m = M + (long)b * 65536 + (long)j * 256;
  float s = 0.f;
  for (int d = 0; d < C; ++d) s += b2f(m[d]) * qkv_b[512 + d];
  cb[b * C + j] = proj_b[j] + s;
}

// ---------------------------------------------------------------------------
// Fused conv3x3 implicit-GEMM + attention-output GEMM, BK=64 (r8, proven:
// 104us, MfmaUtil 35%, 0 bank conflicts). 128x128 tile, 4 waves, acc[4][4];
// merged conv+attn accumulator. 10 taps (9 conv + 1 attn) x 4 chunks of 64-K
// = 40 barrier-steps. 2 LDS buffers [128][64] (64KB -> 2 blocks/CU).
// Slot swizzle: LDS[row][slot] holds global slot (slot ^ (row&7)); read
// applies same XOR. r9's A-direct-global variant regressed 2x (VMEM gather
// serialization) -- A stays in LDS.
__global__ __launch_bounds__(256, 2) void convattn_kernel(
    const u16* __restrict__ xT, const u16* __restrict__ cw,
    const u16* __restrict__ W2, const u16* __restrict__ zbuf,
    const float* __restrict__ conv_b, const float* __restrict__ cb,
    float* __restrict__ out) {
  int b = blockIdx.y;
  int to = blockIdx.x >> 5;  // 0..1
  int tn = blockIdx.x & 31;  // 0..31
  int row0 = to * 128, col0 = tn * 128;
  const u16* xTb = xT + (long)b * CN;
  const u16* W2b = W2 + (long)b * 65536;

  __shared__ u16 lA[2][8192];   // [128][64] u16 per buffer
  __shared__ u16 lB[2][8192];

  int tid = threadIdx.x;
  int lane = tid & 63, w = tid >> 6;
  int wm = w >> 1, wn = w & 1;
  int fr = lane & 15, kq = lane >> 4;
  int fx = fr & 7;              // == row&7 for all fragment rows

  // staging decomp: each wave stages rows [w*32, w*32+32), 4 instrs of 8 rows
  int lr = lane >> 3, sl = lane & 7;
  int ss = sl ^ lr;             // swizzled source slot (row&7 == lr)

  const u16* aA[4]; const u16* pBt[4]; int hh[4], ww[4];
  const u16* zsrc = zbuf + ss * 8;
#pragma unroll
  for (int i = 0; i < 4; ++i) {
    int r = w * 32 + i * 8 + lr;
    aA[i] = cw + (long)(row0 + r) * 2304 + ss * 8;
    int t = col0 + r;
    hh[i] = t >> 6; ww[i] = t & 63;
    pBt[i] = xTb + (long)t * 256 + ss * 8;
  }
  int nb = col0 >> 8, jb = col0 & 255;

  f32x4 acc[4][4] = {};
  const u16 *at0, *at1, *at2, *at3, *bt0, *bt1, *bt2, *bt3;

  auto set_tap = [&](int tap) {
    int dh = tap / 3 - 1, dw = tap % 3 - 1;
    long sh = (long)(dh * 64 + dw) * 256;
    at0 = aA[0] + tap * 256; at1 = aA[1] + tap * 256;
    at2 = aA[2] + tap * 256; at3 = aA[3] + tap * 256;
    bool v0 = ((unsigned)(hh[0] + dh) < 64u) && ((unsigned)(ww[0] + dw) < 64u);
    bool v1 = ((unsigned)(hh[1] + dh) < 64u) && ((unsigned)(ww[1] + dw) < 64u);
    bool v2 = ((unsigned)(hh[2] + dh) < 64u) && ((unsigned)(ww[2] + dw) < 64u);
    bool v3 = ((unsigned)(hh[3] + dh) < 64u) && ((unsigned)(ww[3] + dw) < 64u);
    bt0 = v0 ? pBt[0] + sh : zsrc;
    bt1 = v1 ? pBt[1] + sh : zsrc;
    bt2 = v2 ? pBt[2] + sh : zsrc;
    bt3 = v3 ? pBt[3] + sh : zsrc;
  };
  auto set_attn = [&]() {
#pragma unroll
    for (int i = 0; i < 4; ++i) {
      int r = w * 32 + i * 8 + lr;
      const u16* a = xTb + (long)((row0 + r) * 16 + nb) * 256 + ss * 8;
      const u16* bb = W2b + (long)(jb + r) * 256 + ss * 8;
      if (i == 0) { at0 = a; bt0 = bb; }
      else if (i == 1) { at1 = a; bt1 = bb; }
      else if (i == 2) { at2 = a; bt2 = bb; }
      else { at3 = a; bt3 = bb; }
    }
  };

  auto STAGE = [&](int buf, int chunk) {
    int k = chunk * 64;
    glds16(at0 + k, &lA[buf][(w * 32 + 0) * 64]);
    glds16(at1 + k, &lA[buf][(w * 32 + 8) * 64]);
    glds16(at2 + k, &lA[buf][(w * 32 + 16) * 64]);
    glds16(at3 + k, &lA[buf][(w * 32 + 24) * 64]);
    glds16(bt0 + k, &lB[buf][(w * 32 + 0) * 64]);
    glds16(bt1 + k, &lB[buf][(w * 32 + 8) * 64]);
    glds16(bt2 + k, &lB[buf][(w * 32 + 16) * 64]);
    glds16(bt3 + k, &lB[buf][(w * 32 + 24) * 64]);
  };
  auto COMPUTE = [&](int buf) {
    bf16x8 af[4][2], bf[4][2];
#pragma unroll
    for (int m = 0; m < 4; ++m) {
      int row = wm * 64 + m * 16 + fr;
#pragma unroll
      for (int kh = 0; kh < 2; ++kh)
        af[m][kh] = *(const bf16x8*)&lA[buf][row * 64 + (((kh << 2) + kq) ^ fx) * 8];
    }
#pragma unroll
    for (int n = 0; n < 4; ++n) {
      int row = wn * 64 + n * 16 + fr;
#pragma unroll
      for (int kh = 0; kh < 2; ++kh)
        bf[n][kh] = *(const bf16x8*)&lB[buf][row * 64 + (((kh << 2) + kq) ^ fx) * 8];
    }
    __builtin_amdgcn_s_setprio(1);
#pragma unroll
    for (int kh = 0; kh < 2; ++kh)
#pragma unroll
      for (int m = 0; m < 4; ++m)
#pragma unroll
        for (int n = 0; n < 4; ++n)
          acc[m][n] = __builtin_amdgcn_mfma_f32_16x16x32_bf16(af[m][kh], bf[n][kh], acc[m][n], 0, 0, 0);
    __builtin_amdgcn_s_setprio(0);
  };

  set_tap(0);
  STAGE(0, 0);
  asm volatile("s_waitcnt vmcnt(0)" ::: "memory");
  __builtin_amdgcn_sched_barrier(0);
  __builtin_amdgcn_s_barrier();
  __builtin_amdgcn_sched_barrier(0);

  int buf = 0;
#pragma unroll 1
  for (int T = 0; T < 10; ++T) {
#pragma unroll
    for (int j = 0; j < 4; ++j) {
      if (!(T == 9 && j == 3)) {
        if (j < 3) {
          STAGE(buf ^ 1, j + 1);
        } else {
          if (T < 8) set_tap(T + 1);
          else set_attn();
          STAGE(buf ^ 1, 0);
        }
      }
      COMPUTE(buf);
      asm volatile("s_waitcnt vmcnt(0)" ::: "memory");
      __builtin_amdgcn_sched_barrier(0);
      __builtin_amdgcn_s_barrier();
      __builtin_amdgcn_sched_barrier(0);
      buf ^= 1;
    }
  }

  float* ob = out + (long)b * CN;
  const float* cbb = cb + b * C;
#pragma unroll
  for (int m = 0; m < 4; ++m) {
    int go = row0 + wm * 64 + m * 16 + kq * 4;
#pragma unroll
    for (int nn = 0; nn < 4; ++nn) {
      int cc = wn * 64 + nn * 16 + fr;
      float cbv = cbb[jb + cc];
#pragma unroll
      for (int r = 0; r < 4; ++r)
        ob[(long)(go + r) * NTOK + col0 + cc] =
            acc[m][nn][r] + conv_b[go + r] + cbv;
    }
  }
}

// ---------------------------------------------------------------------------
extern "C" void kernel_launch(void* const* d_in, const int* in_sizes, int n_in,
                              void* d_out, int out_size, void* d_ws, size_t ws_size,
                              hipStream_t stream) {
  const float* x = (const float*)d_in[0];
  const float* qkv_w = (const float*)d_in[1];
  const float* qkv_b = (const float*)d_in[2];
  const float* proj_w = (const float*)d_in[3];
  const float* proj_b = (const float*)d_in[4];
  const float* conv_w = (const float*)d_in[5];
  const float* conv_b = (const float*)d_in[6];
  float* out = (float*)d_out;
  char* ws = (char*)d_ws;

  u16* xbf = (u16*)(ws);                    // 32 MB
  u16* xT = (u16*)(ws + 33554432);          // 32 MB
  u16* Gbf = (u16*)(ws + 67108864);         // 2 MB
  float* Gpart = (float*)(ws + 69206016);   // union w/ T1bf (dead after reduceG)
  u16* T1bf = (u16*)(ws + 69206016);
  float* Sf = (float*)(ws + 71303168);
  u16* attnT = (u16*)(ws + 75497472);
  u16* Mbf = (u16*)(ws + 77594624);
  u16* W2bf = (u16*)(ws + 79691776);
  u16* Wq = (u16*)(ws + 85983232);
  u16* Wk = (u16*)(ws + 86114304);
  u16* WvT = (u16*)(ws + 86245376);
  u16* Pw = (u16*)(ws + 86376448);
  u16* cw = (u16*)(ws + 86507520);
  float* rws = (float*)(ws + 87687168);
  float* uws = (float*)(ws + 87703552);
  float* wws = (float*)(ws + 87719936);
  float* cb = (float*)(ws + 87736320);
  u16* zbuf = (u16*)(ws + 87752704);

  prep_w_kernel<<<3328, 256, 0, stream>>>(qkv_w, proj_w, conv_w, Wq, Wk, WvT,
                                          Pw, cw, rws, zbuf);
  prep_x_kernel<<<dim3(128, 8, BATCH), 256, 0, stream>>>(x, xbf, xT, rws);

  // G = X*X^T per batch, split-K x4 -> f32 partials
  gemm_glds_kernel<0><<<dim3(4, 4, BATCH), 256, 0, stream>>>(
      xbf, xbf, Gpart, 1024, 4096, 4096, 256, 2, CN, CN, 65536,
      0.f, nullptr, nullptr, nullptr, nullptr, 0);
  // reduce split-K partials + bias_uw (independent) in one launch
  reduceG_bias_kernel<<<dim3(65, BATCH), 256, 0, stream>>>(
      Gpart, Gbf, qkv_w, rws, uws, wws);

  // T1 = Wq * G  (G symmetric)
  gemm_glds_kernel<1><<<dim3(4, 1, BATCH), 256, 0, stream>>>(
      Wq, Gbf, T1bf, 256, 256, 256, 256, 2, 0, 65536, 65536,
      0.f, nullptr, nullptr, nullptr, nullptr, 0);
  // S = (T1 * Wk^T + bias terms) * scale
  gemm_glds_kernel<2><<<dim3(4, 1, BATCH), 256, 0, stream>>>(
      T1bf, Wk, Sf, 256, 256, 256, 256, 2, 65536, 0, 65536,
      0.0625f, qkv_b, qkv_b + 256, uws, wws, 256);

  softmax_kernel<<<BATCH * C, 256, 0, stream>>>(Sf, attnT);

  // M = Pw * attn   (B operand = attn^T)
  gemm_glds_kernel<1><<<dim3(4, 1, BATCH), 256, 0, stream>>>(
      Pw, attnT, Mbf, 256, 256, 256, 256, 2, 0, 65536, 65536,
      0.f, nullptr, nullptr, nullptr, nullptr, 0);
  cbias_kernel<<<BATCH, 256, 0, stream>>>(Mbf, qkv_b, proj_b, cb);
  // W2 = M * Wv     (B operand = WvT)
  gemm_glds_kernel<1><<<dim3(4, 1, BATCH), 256, 0, stream>>>(
      Mbf, WvT, W2bf, 256, 256, 256, 256, 2, 65536, 0, 65536,
      0.f, nullptr, nullptr, nullptr, nullptr, 0);

  // fused conv + attention-output, single store of out
  convattn_kernel<<<dim3(64, BATCH), 256, 0, stream>>>(xT, cw, W2bf, zbuf,
                                                       conv_b, cb, out);
}

// Round 11
// 214.757 us; speedup vs baseline: 1.4423x; 1.0062x over previous
//
#include <hip/hip_runtime.h>
#include <hip/hip_bf16.h>

typedef unsigned short u16;
typedef __bf16 bf16x8 __attribute__((ext_vector_type(8)));
typedef float f32x4 __attribute__((ext_vector_type(4)));

#define BATCH 16
#define C 256
#define NTOK 4096      // H*W
#define CN 1048576     // C*NTOK

__device__ __forceinline__ u16 f2b(float f) {
  __hip_bfloat16 h = __float2bfloat16(f);
  return __builtin_bit_cast(u16, h);
}
__device__ __forceinline__ float b2f(u16 u) {
  unsigned int x = ((unsigned int)u) << 16;
  return __builtin_bit_cast(float, x);
}

// async global->LDS, 16B per lane. LDS dest must be wave-uniform base
// (HW adds lane*16); global src is per-lane.
__device__ __forceinline__ void glds16(const u16* g, u16* l) {
  __builtin_amdgcn_global_load_lds(
      (const __attribute__((address_space(1))) unsigned int*)(g),
      (__attribute__((address_space(3))) unsigned int*)(l), 16, 0, 0);
}

// ---------------------------------------------------------------------------
// prep_x: x f32 [B][C][N] -> xbf [B][C][N], xT [B][N][C]; row partial sums
// atomically into rws (rws zeroed by prep_w, launched before).
__global__ __launch_bounds__(256) void prep_x_kernel(
    const float* __restrict__ x, u16* __restrict__ xbf, u16* __restrict__ xT,
    float* __restrict__ rws) {
  __shared__ float t[32][33];
  int b = blockIdx.z;
  int c0 = blockIdx.y * 32, n0 = blockIdx.x * 32;
  int tid = threadIdx.x;
  int i = tid >> 3, j4 = (tid & 7) * 4;
  const float* xb = x + (long)b * CN;
  float4 v = *(const float4*)(xb + (long)(c0 + i) * NTOK + n0 + j4);
  ushort4 bv;
  bv.x = f2b(v.x); bv.y = f2b(v.y); bv.z = f2b(v.z); bv.w = f2b(v.w);
  *(ushort4*)(xbf + (long)b * CN + (long)(c0 + i) * NTOK + n0 + j4) = bv;
  t[i][j4 + 0] = v.x; t[i][j4 + 1] = v.y; t[i][j4 + 2] = v.z; t[i][j4 + 3] = v.w;
  __syncthreads();
  ushort4 o;
  o.x = f2b(t[j4 + 0][i]); o.y = f2b(t[j4 + 1][i]);
  o.z = f2b(t[j4 + 2][i]); o.w = f2b(t[j4 + 3][i]);
  *(ushort4*)(xT + (long)b * CN + (long)(n0 + i) * C + c0 + j4) = o;
  if (tid < 32) {
    float s = 0.f;
#pragma unroll
    for (int j = 0; j < 32; ++j) s += t[tid][j];
    atomicAdd(&rws[b * C + c0 + tid], s);
  }
}

// ---------------------------------------------------------------------------
// prep_w: WqT (transposed Wq, for reduceG_T1 matvec), Wk, WvT, Pw, cw.
__global__ __launch_bounds__(256) void prep_w_kernel(
    const float* __restrict__ qkv_w, const float* __restrict__ proj_w,
    const float* __restrict__ conv_w, u16* __restrict__ WqT, u16* __restrict__ Wk,
    u16* __restrict__ WvT, u16* __restrict__ Pw, u16* __restrict__ cw,
    float* __restrict__ rws, u16* __restrict__ zbuf) {
  int idx = blockIdx.x * 256 + threadIdx.x;
  if (idx < 4096) rws[idx] = 0.f;
  if (idx < 256) zbuf[idx] = 0;
  if (idx < 65536) {
    // WqT[k][r] = Wq[r][k]; coalesced read, scattered write
    WqT[(idx & 255) * 256 + (idx >> 8)] = f2b(qkv_w[idx]);
  } else if (idx < 131072) {
    int e = idx - 65536;
    Wk[e] = f2b(qkv_w[65536 + e]);
  } else if (idx < 196608) {
    int e = idx - 131072;
    int i = e >> 8, d = e & 255;
    WvT[e] = f2b(qkv_w[131072 + d * 256 + i]);
  } else if (idx < 262144) {
    int e = idx - 196608;
    Pw[e] = f2b(proj_w[e]);
  } else if (idx < 851968) {
    int e = idx - 262144;
    int o = e / 2304;
    int rem = e - o * 2304;
    int tap = rem >> 8, i = rem & 255;
    cw[e] = f2b(conv_w[o * 2304 + i * 9 + tap]);
  }
}

// ---------------------------------------------------------------------------
// Generic GEMM C = A*B^T (both K-contiguous), 128x128 tile, BK=32, 4 waves,
// global_load_lds staging + slot-XOR swizzle, double-buffered.
// EPI 0: f32 partial store. EPI 1: bf16. EPI 2: S-epi. EPI 4: bf16 + extra
// cbias block at blockIdx.x==4 (e1=qkv_b, e2=proj_b, e4=cb output).
template <int EPI>
__global__ __launch_bounds__(256, 2) void gemm_glds_kernel(
    const u16* __restrict__ A, const u16* __restrict__ B, void* __restrict__ Cv,
    int K, int lda, int ldb, int ldc, int tilesN, long sA, long sB, long sC,
    float scale, const float* __restrict__ e1, const float* __restrict__ e2,
    const float* __restrict__ e3, const float* __restrict__ e4, int e34stride) {
  if (EPI == 4 && blockIdx.x == 4) {
    // cbias: cb[b][j] = proj_b[j] + sum_d M[b][j][d]*qkv_b[512+d]
    int bb = blockIdx.z, j = threadIdx.x;
    const u16* m = A + (long)bb * sA + (long)j * 256;
    float s = 0.f;
    for (int d = 0; d < 256; ++d) s += b2f(m[d]) * e1[512 + d];
    float* cbout = const_cast<float*>(e4);
    cbout[bb * 256 + j] = e2[j] + s;
    return;
  }
  int b = blockIdx.z, ks = blockIdx.y;
  A += (long)b * sA + (long)ks * K;
  B += (long)b * sB + (long)ks * K;
  int ty = blockIdx.x / tilesN, tx = blockIdx.x % tilesN;
  int row0 = ty * 128, col0 = tx * 128;

  __shared__ u16 lA[2][4096];
  __shared__ u16 lB[2][4096];

  int tid = threadIdx.x;
  int lane = tid & 63, wv = tid >> 6;
  int wm = wv >> 1, wn = wv & 1;
  int fr = lane & 15, kq = lane >> 4;
  int kqs = kq ^ ((fr >> 1) & 3);

  int c0 = wv * 128 + lane, c1 = c0 + 64;
  int r0s = c0 >> 2, r1s = c1 >> 2;
  int ls0 = (c0 & 3) ^ ((r0s >> 1) & 3);
  int ls1 = (c1 & 3) ^ ((r1s >> 1) & 3);
  const u16* pA0 = A + (long)(row0 + r0s) * lda + ls0 * 8;
  const u16* pA1 = A + (long)(row0 + r1s) * lda + ls1 * 8;
  const u16* pB0 = B + (long)(col0 + r0s) * ldb + ls0 * 8;
  const u16* pB1 = B + (long)(col0 + r1s) * ldb + ls1 * 8;
  int dst0 = wv * 1024, dst1 = wv * 1024 + 512;

  f32x4 acc[4][4] = {};

  auto STAGE = [&](int buf, int t) {
    int k0 = t << 5;
    glds16(pA0 + k0, &lA[buf][dst0]);
    glds16(pA1 + k0, &lA[buf][dst1]);
    glds16(pB0 + k0, &lB[buf][dst0]);
    glds16(pB1 + k0, &lB[buf][dst1]);
  };
  auto COMPUTE = [&](int buf) {
    bf16x8 af[4], bfr[4];
#pragma unroll
    for (int m = 0; m < 4; ++m)
      af[m] = *(const bf16x8*)&lA[buf][(wm * 64 + m * 16 + fr) * 32 + kqs * 8];
#pragma unroll
    for (int n = 0; n < 4; ++n)
      bfr[n] = *(const bf16x8*)&lB[buf][(wn * 64 + n * 16 + fr) * 32 + kqs * 8];
#pragma unroll
    for (int m = 0; m < 4; ++m)
#pragma unroll
      for (int n = 0; n < 4; ++n)
        acc[m][n] = __builtin_amdgcn_mfma_f32_16x16x32_bf16(af[m], bfr[n], acc[m][n], 0, 0, 0);
  };

  int nk = K >> 5, cur = 0;
  STAGE(0, 0);
  __syncthreads();
  for (int t = 0; t < nk; ++t) {
    if (t + 1 < nk) STAGE(cur ^ 1, t + 1);
    COMPUTE(cur);
    __syncthreads();
    cur ^= 1;
  }

  if (EPI == 0) {
    float* Cb = (float*)Cv + ((long)b * 4 + ks) * sC;
#pragma unroll
    for (int m = 0; m < 4; ++m)
#pragma unroll
      for (int n = 0; n < 4; ++n)
#pragma unroll
        for (int r = 0; r < 4; ++r) {
          int gr = row0 + wm * 64 + m * 16 + kq * 4 + r;
          int gc = col0 + wn * 64 + n * 16 + fr;
          Cb[(long)gr * ldc + gc] = acc[m][n][r];
        }
  } else if (EPI == 1 || EPI == 4) {
    __hip_bfloat16* Cb = (__hip_bfloat16*)Cv + (long)b * sC;
#pragma unroll
    for (int m = 0; m < 4; ++m)
#pragma unroll
      for (int n = 0; n < 4; ++n)
#pragma unroll
        for (int r = 0; r < 4; ++r) {
          int gr = row0 + wm * 64 + m * 16 + kq * 4 + r;
          int gc = col0 + wn * 64 + n * 16 + fr;
          Cb[(long)gr * ldc + gc] = __float2bfloat16(acc[m][n][r]);
        }
  } else if (EPI == 2) {
    float* Cb = (float*)Cv + (long)b * sC;
    const float* ub = e3 + (long)b * e34stride;
    const float* wb = e4 + (long)b * e34stride;
#pragma unroll
    for (int m = 0; m < 4; ++m)
#pragma unroll
      for (int n = 0; n < 4; ++n)
#pragma unroll
        for (int r = 0; r < 4; ++r) {
          int gr = row0 + wm * 64 + m * 16 + kq * 4 + r;
          int gc = col0 + wn * 64 + n * 16 + fr;
          float v = acc[m][n][r] + e1[gr] * ub[gc] + e2[gc] * wb[gr] +
                    4096.0f * e1[gr] * e2[gc];
          Cb[(long)gr * ldc + gc] = v * scale;
        }
  }
}

// ---------------------------------------------------------------------------
// reduceG + T1 + bias_uw merged. grid (65, B):
// x<64: sum 4 split-K partials of G rows [4x..4x+4) (f32), then since G is
//       symmetric, T1[c][d] = sum_i Wq[c,i]*G[d,i] -> thread c computes the
//       4 T1 columns d=4x..4x+3 via WqT (coalesced bf16) x LDS g (broadcast).
//       G itself is never materialized (Gbf slot now holds T1).
// x==64: u[b][t]=Wk[t,:]*r[b,:], w[b][t]=Wq[t,:]*r[b,:].
__global__ __launch_bounds__(256) void reduceG_T1_bias_kernel(
    const float* __restrict__ Gp, const u16* __restrict__ WqT,
    u16* __restrict__ T1, const float* __restrict__ qkv_w,
    const float* __restrict__ r, float* __restrict__ u, float* __restrict__ w) {
  int b = blockIdx.y;
  if (blockIdx.x < 64) {
    __shared__ float g[4][256];
    int tid = threadIdx.x;
    int e = blockIdx.x * 1024 + tid * 4;
    const float* base = Gp + (long)b * 262144;
    float4 s = *(const float4*)(base + e);
#pragma unroll
    for (int sl = 1; sl < 4; ++sl) {
      float4 v = *(const float4*)(base + sl * 65536 + e);
      s.x += v.x; s.y += v.y; s.z += v.z; s.w += v.w;
    }
    int rr = tid >> 6, cc = (tid & 63) * 4;
    g[rr][cc + 0] = s.x; g[rr][cc + 1] = s.y;
    g[rr][cc + 2] = s.z; g[rr][cc + 3] = s.w;
    __syncthreads();
    int c = tid;
    float a0 = 0.f, a1 = 0.f, a2 = 0.f, a3 = 0.f;
#pragma unroll 4
    for (int i = 0; i < 256; ++i) {
      float wq = b2f(WqT[i * 256 + c]);
      a0 += wq * g[0][i]; a1 += wq * g[1][i];
      a2 += wq * g[2][i]; a3 += wq * g[3][i];
    }
    ushort4 o;
    o.x = f2b(a0); o.y = f2b(a1); o.z = f2b(a2); o.w = f2b(a3);
    *(ushort4*)(T1 + (long)b * 65536 + (long)c * 256 + blockIdx.x * 4) = o;
  } else {
    int t = threadIdx.x;
    const float* rb = r + b * C;
    float su = 0.f, sw = 0.f;
    for (int i = 0; i < C; ++i) {
      float rv = rb[i];
      su += qkv_w[(256 + t) * 256 + i] * rv;
      sw += qkv_w[t * 256 + i] * rv;
    }
    u[b * C + t] = su;
    w[b * C + t] = sw;
  }
}

// ---------------------------------------------------------------------------
// softmax over rows of S -> attn^T bf16 (attnT[d][c] = attn[c][d])
__global__ __launch_bounds__(256) void softmax_kernel(const float* __restrict__ S,
                                                      u16* __restrict__ attnT) {
  int row = blockIdx.x;
  int t = threadIdx.x;
  float v = S[(long)row * C + t];
  __shared__ float red[256];
  red[t] = v; __syncthreads();
  for (int st = 128; st > 0; st >>= 1) {
    if (t < st) red[t] = fmaxf(red[t], red[t + st]);
    __syncthreads();
  }
  float mx = red[0];
  __syncthreads();
  float e = __expf(v - mx);
  red[t] = e; __syncthreads();
  for (int st = 128; st > 0; st >>= 1) {
    if (t < st) red[t] += red[t + st];
    __syncthreads();
  }
  float inv = 1.0f / red[0];
  int b = row >> 8, c = row & 255;
  attnT[(long)b * 65536 + t * 256 + c] = f2b(e * inv);
}

// ---------------------------------------------------------------------------
// Fused conv3x3 implicit-GEMM + attention-output GEMM, BK=64 (proven:
// 104us, MfmaUtil 36%, 0 bank conflicts). 128x128 tile, 4 waves, acc[4][4];
// merged conv+attn accumulator. 10 taps (9 conv + 1 attn) x 4 chunks of 64-K
// = 40 barrier-steps. 2 LDS buffers [128][64] (64KB -> 2 blocks/CU).
// Slot swizzle: LDS[row][slot] holds global slot (slot ^ (row&7)); read
// applies same XOR.
__global__ __launch_bounds__(256, 2) void convattn_kernel(
    const u16* __restrict__ xT, const u16* __restrict__ cw,
    const u16* __restrict__ W2, const u16* __restrict__ zbuf,
    const float* __restrict__ conv_b, const float* __restrict__ cb,
    float* __restrict__ out) {
  int b = blockIdx.y;
  int to = blockIdx.x >> 5;  // 0..1
  int tn = blockIdx.x & 31;  // 0..31
  int row0 = to * 128, col0 = tn * 128;
  const u16* xTb = xT + (long)b * CN;
  const u16* W2b = W2 + (long)b * 65536;

  __shared__ u16 lA[2][8192];   // [128][64] u16 per buffer
  __shared__ u16 lB[2][8192];

  int tid = threadIdx.x;
  int lane = tid & 63, w = tid >> 6;
  int wm = w >> 1, wn = w & 1;
  int fr = lane & 15, kq = lane >> 4;
  int fx = fr & 7;              // == row&7 for all fragment rows

  // staging decomp: each wave stages rows [w*32, w*32+32), 4 instrs of 8 rows
  int lr = lane >> 3, sl = lane & 7;
  int ss = sl ^ lr;             // swizzled source slot (row&7 == lr)

  const u16* aA[4]; const u16* pBt[4]; int hh[4], ww[4];
  const u16* zsrc = zbuf + ss * 8;
#pragma unroll
  for (int i = 0; i < 4; ++i) {
    int r = w * 32 + i * 8 + lr;
    aA[i] = cw + (long)(row0 + r) * 2304 + ss * 8;
    int t = col0 + r;
    hh[i] = t >> 6; ww[i] = t & 63;
    pBt[i] = xTb + (long)t * 256 + ss * 8;
  }
  int nb = col0 >> 8, jb = col0 & 255;

  f32x4 acc[4][4] = {};
  const u16 *at0, *at1, *at2, *at3, *bt0, *bt1, *bt2, *bt3;

  auto set_tap = [&](int tap) {
    int dh = tap / 3 - 1, dw = tap % 3 - 1;
    long sh = (long)(dh * 64 + dw) * 256;
    at0 = aA[0] + tap * 256; at1 = aA[1] + tap * 256;
    at2 = aA[2] + tap * 256; at3 = aA[3] + tap * 256;
    bool v0 = ((unsigned)(hh[0] + dh) < 64u) && ((unsigned)(ww[0] + dw) < 64u);
    bool v1 = ((unsigned)(hh[1] + dh) < 64u) && ((unsigned)(ww[1] + dw) < 64u);
    bool v2 = ((unsigned)(hh[2] + dh) < 64u) && ((unsigned)(ww[2] + dw) < 64u);
    bool v3 = ((unsigned)(hh[3] + dh) < 64u) && ((unsigned)(ww[3] + dw) < 64u);
    bt0 = v0 ? pBt[0] + sh : zsrc;
    bt1 = v1 ? pBt[1] + sh : zsrc;
    bt2 = v2 ? pBt[2] + sh : zsrc;
    bt3 = v3 ? pBt[3] + sh : zsrc;
  };
  auto set_attn = [&]() {
#pragma unroll
    for (int i = 0; i < 4; ++i) {
      int r = w * 32 + i * 8 + lr;
      const u16* a = xTb + (long)((row0 + r) * 16 + nb) * 256 + ss * 8;
      const u16* bb = W2b + (long)(jb + r) * 256 + ss * 8;
      if (i == 0) { at0 = a; bt0 = bb; }
      else if (i == 1) { at1 = a; bt1 = bb; }
      else if (i == 2) { at2 = a; bt2 = bb; }
      else { at3 = a; bt3 = bb; }
    }
  };

  auto STAGE = [&](int buf, int chunk) {
    int k = chunk * 64;
    glds16(at0 + k, &lA[buf][(w * 32 + 0) * 64]);
    glds16(at1 + k, &lA[buf][(w * 32 + 8) * 64]);
    glds16(at2 + k, &lA[buf][(w * 32 + 16) * 64]);
    glds16(at3 + k, &lA[buf][(w * 32 + 24) * 64]);
    glds16(bt0 + k, &lB[buf][(w * 32 + 0) * 64]);
    glds16(bt1 + k, &lB[buf][(w * 32 + 8) * 64]);
    glds16(bt2 + k, &lB[buf][(w * 32 + 16) * 64]);
    glds16(bt3 + k, &lB[buf][(w * 32 + 24) * 64]);
  };
  auto COMPUTE = [&](int buf) {
    bf16x8 af[4][2], bf[4][2];
#pragma unroll
    for (int m = 0; m < 4; ++m) {
      int row = wm * 64 + m * 16 + fr;
#pragma unroll
      for (int kh = 0; kh < 2; ++kh)
        af[m][kh] = *(const bf16x8*)&lA[buf][row * 64 + (((kh << 2) + kq) ^ fx) * 8];
    }
#pragma unroll
    for (int n = 0; n < 4; ++n) {
      int row = wn * 64 + n * 16 + fr;
#pragma unroll
      for (int kh = 0; kh < 2; ++kh)
        bf[n][kh] = *(const bf16x8*)&lB[buf][row * 64 + (((kh << 2) + kq) ^ fx) * 8];
    }
    __builtin_amdgcn_s_setprio(1);
#pragma unroll
    for (int kh = 0; kh < 2; ++kh)
#pragma unroll
      for (int m = 0; m < 4; ++m)
#pragma unroll
        for (int n = 0; n < 4; ++n)
          acc[m][n] = __builtin_amdgcn_mfma_f32_16x16x32_bf16(af[m][kh], bf[n][kh], acc[m][n], 0, 0, 0);
    __builtin_amdgcn_s_setprio(0);
  };

  set_tap(0);
  STAGE(0, 0);
  asm volatile("s_waitcnt vmcnt(0)" ::: "memory");
  __builtin_amdgcn_sched_barrier(0);
  __builtin_amdgcn_s_barrier();
  __builtin_amdgcn_sched_barrier(0);

  int buf = 0;
#pragma unroll 1
  for (int T = 0; T < 10; ++T) {
#pragma unroll
    for (int j = 0; j < 4; ++j) {
      if (!(T == 9 && j == 3)) {
        if (j < 3) {
          STAGE(buf ^ 1, j + 1);
        } else {
          if (T < 8) set_tap(T + 1);
          else set_attn();
          STAGE(buf ^ 1, 0);
        }
      }
      COMPUTE(buf);
      asm volatile("s_waitcnt vmcnt(0)" ::: "memory");
      __builtin_amdgcn_sched_barrier(0);
      __builtin_amdgcn_s_barrier();
      __builtin_amdgcn_sched_barrier(0);
      buf ^= 1;
    }
  }

  float* ob = out + (long)b * CN;
  const float* cbb = cb + b * C;
#pragma unroll
  for (int m = 0; m < 4; ++m) {
    int go = row0 + wm * 64 + m * 16 + kq * 4;
#pragma unroll
    for (int nn = 0; nn < 4; ++nn) {
      int cc = wn * 64 + nn * 16 + fr;
      float cbv = cbb[jb + cc];
#pragma unroll
      for (int r = 0; r < 4; ++r)
        ob[(long)(go + r) * NTOK + col0 + cc] =
            acc[m][nn][r] + conv_b[go + r] + cbv;
    }
  }
}

// ---------------------------------------------------------------------------
extern "C" void kernel_launch(void* const* d_in, const int* in_sizes, int n_in,
                              void* d_out, int out_size, void* d_ws, size_t ws_size,
                              hipStream_t stream) {
  const float* x = (const float*)d_in[0];
  const float* qkv_w = (const float*)d_in[1];
  const float* qkv_b = (const float*)d_in[2];
  const float* proj_w = (const float*)d_in[3];
  const float* proj_b = (const float*)d_in[4];
  const float* conv_w = (const float*)d_in[5];
  const float* conv_b = (const float*)d_in[6];
  float* out = (float*)d_out;
  char* ws = (char*)d_ws;

  u16* xbf = (u16*)(ws);                    // 32 MB
  u16* xT = (u16*)(ws + 33554432);          // 32 MB
  u16* T1bf = (u16*)(ws + 67108864);        // 2 MB (old Gbf slot; G never materialized)
  float* Gpart = (float*)(ws + 69206016);   // 16.7 MB, dead after reduceG_T1
  float* Sf = (float*)(ws + 71303168);      // union w/ Gpart (written after)
  u16* attnT = (u16*)(ws + 75497472);
  u16* Mbf = (u16*)(ws + 77594624);
  u16* W2bf = (u16*)(ws + 79691776);
  u16* WqT = (u16*)(ws + 85983232);
  u16* Wk = (u16*)(ws + 86114304);
  u16* WvT = (u16*)(ws + 86245376);
  u16* Pw = (u16*)(ws + 86376448);
  u16* cw = (u16*)(ws + 86507520);
  float* rws = (float*)(ws + 87687168);
  float* uws = (float*)(ws + 87703552);
  float* wws = (float*)(ws + 87719936);
  float* cb = (float*)(ws + 87736320);
  u16* zbuf = (u16*)(ws + 87752704);

  prep_w_kernel<<<3328, 256, 0, stream>>>(qkv_w, proj_w, conv_w, WqT, Wk, WvT,
                                          Pw, cw, rws, zbuf);
  prep_x_kernel<<<dim3(128, 8, BATCH), 256, 0, stream>>>(x, xbf, xT, rws);

  // G = X*X^T per batch, split-K x4 -> f32 partials
  gemm_glds_kernel<0><<<dim3(4, 4, BATCH), 256, 0, stream>>>(
      xbf, xbf, Gpart, 1024, 4096, 4096, 256, 2, CN, CN, 65536,
      0.f, nullptr, nullptr, nullptr, nullptr, 0);
  // reduce split-K partials -> T1 directly (G symmetric) + bias_uw
  reduceG_T1_bias_kernel<<<dim3(65, BATCH), 256, 0, stream>>>(
      Gpart, WqT, T1bf, qkv_w, rws, uws, wws);

  // S = (T1 * Wk^T + bias terms) * scale
  gemm_glds_kernel<2><<<dim3(4, 1, BATCH), 256, 0, stream>>>(
      T1bf, Wk, Sf, 256, 256, 256, 256, 2, 65536, 0, 65536,
      0.0625f, qkv_b, qkv_b + 256, uws, wws, 256);

  softmax_kernel<<<BATCH * C, 256, 0, stream>>>(Sf, attnT);

  // M = Pw * attn   (B operand = attn^T)
  gemm_glds_kernel<1><<<dim3(4, 1, BATCH), 256, 0, stream>>>(
      Pw, attnT, Mbf, 256, 256, 256, 256, 2, 0, 65536, 65536,
      0.f, nullptr, nullptr, nullptr, nullptr, 0);
  // W2 = M * Wv (B operand = WvT); 5th block per batch computes cbias
  gemm_glds_kernel<4><<<dim3(5, 1, BATCH), 256, 0, stream>>>(
      Mbf, WvT, W2bf, 256, 256, 256, 256, 2, 65536, 0, 65536,
      0.f, qkv_b, proj_b, nullptr, cb, 256);

  // fused conv + attention-output, single store of out
  convattn_kernel<<<dim3(64, BATCH), 256, 0, stream>>>(xT, cw, W2bf, zbuf,
                                                       conv_b, cb, out);
}